// Round 12
// baseline (418.005 us; speedup 1.0000x reference)
//
#include <hip/hip_runtime.h>
#include <hip/hip_bf16.h>
#include <stdint.h>

// MLA forward, B=2 S=2048 DIM=2048 NH=16 HD=128 HDR=64 DCKV=512 DCQ=1536
// Round 12: (1) attn: R10's validated VALU cuts (diag-only mask + defer-max)
// re-landed per-row so sv[] stays loop-local -> VGPR stays under the 128
// cliff (R10's regression was the sv[4][4] hoist: 116->132 VGPR).
// (2) conv launch fusion: 9 tiny launches -> 2 multi-job launches.
// Everything else byte-identical to R11 (357us, verified).
//
// Reference reshape quirk: q = concat([uq(2048), rq(1024)]).reshape(...,16,192)
// -> head h owns FLAT dims [192h,192h+192) of the concat (same for k).

typedef __bf16 bf16x8 __attribute__((ext_vector_type(8)));
typedef float  f32x4  __attribute__((ext_vector_type(4)));

__device__ __forceinline__ uint16_t f2bf(float f) {
    uint32_t u = __builtin_bit_cast(uint32_t, f);
    u = (u + 0x7FFFu + ((u >> 16) & 1u)) >> 16;
    return (uint16_t)u;
}
__device__ __forceinline__ float bf2f(uint16_t h) {
    uint32_t u = ((uint32_t)h) << 16;
    return __builtin_bit_cast(float, u);
}

typedef __attribute__((address_space(3))) uint32_t lds_u32_t;
typedef const __attribute__((address_space(1))) uint32_t glb_u32_t;

__device__ __forceinline__ void gld16(const void* g, const void* l) {
    __builtin_amdgcn_global_load_lds((glb_u32_t*)(uintptr_t)g,
                                     (lds_u32_t*)(uint32_t)(uintptr_t)l, 16, 0, 0);
}

// ---------------------------------------------------------------------------
// Multi-job fp32 -> bf16 conversion. Up to 5 (src,dst) jobs per launch,
// grid-stride-free exact mapping: quad q routes by cumulative dst-quad counts.
// Zero-fills dst quads beyond the job's src quads (W_kr padding).
// ---------------------------------------------------------------------------
__global__ __launch_bounds__(256)
void conv_multi(const float* __restrict__ s0, uint16_t* __restrict__ d0, int q0s, int q0d,
                const float* __restrict__ s1, uint16_t* __restrict__ d1, int q1s, int q1d,
                const float* __restrict__ s2, uint16_t* __restrict__ d2, int q2s, int q2d,
                const float* __restrict__ s3, uint16_t* __restrict__ d3, int q3s, int q3d,
                const float* __restrict__ s4, uint16_t* __restrict__ d4, int q4s, int q4d)
{
    int q = blockIdx.x * 256 + threadIdx.x;
    const float* s; uint16_t* d; int qs;
    if (q < q0d)                    { s = s0; d = d0; qs = q0s; }
    else if ((q -= q0d) < q1d)      { s = s1; d = d1; qs = q1s; }
    else if ((q -= q1d) < q2d)      { s = s2; d = d2; qs = q2s; }
    else if ((q -= q2d) < q3d)      { s = s3; d = d3; qs = q3s; }
    else if ((q -= q3d) < q4d)      { s = s4; d = d4; qs = q4s; }
    else return;
    int i = q << 2;
    ushort4 o;
    if (q < qs) {
        float4 v = *(const float4*)(s + i);
        o.x = f2bf(v.x); o.y = f2bf(v.y); o.z = f2bf(v.z); o.w = f2bf(v.w);
    } else {
        o.x = 0; o.y = 0; o.z = 0; o.w = 0;
    }
    *(ushort4*)(d + i) = o;
}

// ---------------------------------------------------------------------------
// Fused GEMM (R11-verified, unchanged): C(M,N) = A(M,K;lda) @ W(N,K)^T + bias.
// MODE 0: bf16 row-major  MODE 3: fp32 row-major
// MODE 4: qk-pack | FUSED ROPE-Q   MODE 5: qk-pack | v-transpose-pack
// ---------------------------------------------------------------------------
template<int MODE>
__global__ __launch_bounds__(256, 2)
void gemm_fused(const uint16_t* __restrict__ A, const uint16_t* __restrict__ W,
                const float* __restrict__ b0, const float* __restrict__ b1,
                const float* __restrict__ b2,
                const float* __restrict__ fc, const float* __restrict__ fs,
                void* __restrict__ O0, void* __restrict__ O1,
                int M, int N, int K, int lda, int s1, int s2)
{
    __shared__ __align__(16) uint16_t Alds[128 * 32];
    __shared__ __align__(16) uint16_t Blds[128 * 32];

    const int tid  = threadIdx.x;
    const int lane = tid & 63;
    const int wave = tid >> 6;
    const int wm   = wave >> 1;
    const int wn   = wave & 1;
    const int m0   = blockIdx.y << 7;
    const int n0   = blockIdx.x << 7;

    f32x4 acc[4][4];
    #pragma unroll
    for (int i = 0; i < 4; ++i)
        #pragma unroll
        for (int j = 0; j < 4; ++j)
            acc[i][j] = (f32x4){0.f, 0.f, 0.f, 0.f};

    const int r0 = (wave << 5) + (lane >> 2);
    const int ck = (lane & 3) << 3;
    const uint16_t* gA0 = A + (size_t)(m0 + r0) * lda + ck;
    const uint16_t* gA1 = gA0 + (size_t)16 * lda;
    const uint16_t* gB0 = W + (size_t)(n0 + r0) * K + ck;
    const uint16_t* gB1 = gB0 + (size_t)16 * K;
    const uint16_t* lA0 = Alds + (wave << 10);
    const uint16_t* lA1 = lA0 + 512;
    const uint16_t* lB0 = Blds + (wave << 10);
    const uint16_t* lB1 = lB0 + 512;

    const int rsel = lane & 15;
    const int g8   = (lane >> 4) << 3;

    const int nK = K >> 5;
    for (int kt = 0; kt < nK; ++kt) {
        __syncthreads();
        gld16(gA0, lA0); gld16(gA1, lA1);
        gld16(gB0, lB0); gld16(gB1, lB1);
        gA0 += 32; gA1 += 32; gB0 += 32; gB1 += 32;
        __syncthreads();

        bf16x8 af[4], bfr[4];
        #pragma unroll
        for (int i = 0; i < 4; ++i)
            af[i] = *(const bf16x8*)&Alds[(((wm << 6) + (i << 4) + rsel) << 5) + g8];
        #pragma unroll
        for (int j = 0; j < 4; ++j)
            bfr[j] = *(const bf16x8*)&Blds[(((wn << 6) + (j << 4) + rsel) << 5) + g8];

        #pragma unroll
        for (int i = 0; i < 4; ++i)
            #pragma unroll
            for (int j = 0; j < 4; ++j)
                acc[i][j] = __builtin_amdgcn_mfma_f32_16x16x32_bf16(af[i], bfr[j], acc[i][j], 0, 0, 0);
    }

    // epilogue: D lane map: col = lane&15, row = 4*(lane>>4)+r
    const int col = lane & 15;
    const int rg  = lane >> 4;
    #pragma unroll
    for (int i = 0; i < 4; ++i) {
        #pragma unroll
        for (int j = 0; j < 4; ++j) {
            int n = n0 + (wn << 6) + (j << 4) + col;
            if (n >= N) continue;
            float bv = (n < s1) ? b0[n] : (n < s2) ? b1[n - s1] : b2[n - s2];
            float v[4];
            #pragma unroll
            for (int r = 0; r < 4; ++r) v[r] = acc[i][j][r] + bv;
            int mbase = m0 + (wm << 6) + (i << 4) + (rg << 2);
            if (MODE == 0) {
                uint16_t* o = (uint16_t*)O0 + (size_t)mbase * N + n;
                #pragma unroll
                for (int r = 0; r < 4; ++r) o[(size_t)r * N] = f2bf(v[r]);
            } else if (MODE == 3) {
                float* o = (float*)O0 + (size_t)mbase * N + n;
                #pragma unroll
                for (int r = 0; r < 4; ++r) o[(size_t)r * N] = v[r];
            } else {
                int b = mbase >> 11, s = mbase & 2047;
                if (n < s1) {           // qk-pack (n < 2048, hh = n/192)
                    int hh = n / 192, d = n - hh * 192;
                    uint16_t* o = (uint16_t*)O0 + (((size_t)(b * 16 + hh) * 2048 + s) * 192) + d;
                    #pragma unroll
                    for (int r = 0; r < 4; ++r) o[r * 192] = f2bf(v[r]);
                } else if (MODE == 4) { // FUSED ROPE-Q -> qp
                    int nn = n - s1;
                    int d  = nn & 63;
                    float bp = b1[nn ^ 32];
                    int f = 2048 + nn;
                    int head = f / 192, dq = f - head * 192;
                    uint16_t* o = (uint16_t*)O0 + (((size_t)(b * 16 + head) * 2048 + s) * 192) + dq;
                    #pragma unroll
                    for (int r = 0; r < 4; ++r) {
                        float pv  = acc[i][j ^ 2][r] + bp;
                        float rot = (d < 32) ? -pv : pv;
                        int   sl  = s + r;
                        float out = v[r] * fc[(size_t)sl * 64 + d] + rot * fs[(size_t)sl * 64 + d];
                        o[r * 192] = f2bf(out);
                    }
                } else {                // MODE 5: v-transpose pack
                    int nn = n - s1;
                    int hh = nn >> 7, d = nn & 127;
                    ushort4 o4;
                    o4.x = f2bf(v[0]); o4.y = f2bf(v[1]); o4.z = f2bf(v[2]); o4.w = f2bf(v[3]);
                    *(ushort4*)&((uint16_t*)O1)[(((size_t)(b * 16 + hh) * 128 + d) * 2048) + s] = o4;
                }
            }
        }
    }
}

// ---------------------------------------------------------------------------
// rope_k (R11-verified, unchanged)
// ---------------------------------------------------------------------------
__global__ __launch_bounds__(256)
void rope_k_kernel(const uint16_t* __restrict__ raw, int ldr,
                   const float* __restrict__ fc, const float* __restrict__ fs,
                   uint16_t* __restrict__ kp)
{
    int gid = blockIdx.x * 256 + threadIdx.x;
    int m = gid >> 6, d = gid & 63;
    int b = m >> 11, s = m & 2047;
    float x  = bf2f(raw[(size_t)m * ldr + d]);
    float xo = bf2f(raw[(size_t)m * ldr + ((d < 32) ? d + 32 : d - 32)]);
    float rot = (d < 32) ? -xo : xo;
    uint16_t bv = f2bf(x * fc[s * 64 + d] + rot * fs[s * 64 + d]);
    #pragma unroll
    for (int hh = 0; hh < 16; ++hh) {
        int f = 2048 + hh * 64 + d;
        int head = f / 192, dk = f - head * 192;
        kp[(((size_t)(b * 16 + head) * 2048 + s) * 192) + dk] = bv;
    }
}

// ---------------------------------------------------------------------------
// MFMA flash attention (causal). R11 grid (1024 blocks, heavy-first, XCD-
// friendly bh=idx&31) + diag-only masking + per-row defer-max (THR=8, log2).
// sv[] stays loop-local -> VGPR under the 128 cliff.
// ---------------------------------------------------------------------------
__global__ __launch_bounds__(256)
void attn_mfma6(const uint16_t* __restrict__ qp, const uint16_t* __restrict__ kp,
                const uint16_t* __restrict__ vt, uint16_t* __restrict__ yf)
{
    __shared__ uint16_t Ks[64][200];
    __shared__ uint16_t Vs[128][72];
    __shared__ uint16_t Ps[4][16][72];

    const int tid  = threadIdx.x;
    const int lane = tid & 63;
    const int w    = tid >> 6;
    const int g    = lane >> 4;
    const int li   = lane & 15;
    const int idx  = blockIdx.x;
    const int qt   = 31 - (idx >> 5);      // heavy tiles dispatch first
    const int bh   = idx & 31;             // idx%8 == bh%8 -> same-head same-XCD
    const int b    = bh >> 4;
    const int h    = bh & 15;
    const int q0   = qt << 6;

    const size_t qkb = (size_t)bh * 2048 * 192;
    const size_t vtb = (size_t)bh * 128 * 2048;
    const float scl = 0.07216878364870323f * 1.4426950408889634f;  // 1/sqrt(192)*log2e
    const float NEGINF = -__builtin_inff();

    bf16x8 qf[6];
    #pragma unroll
    for (int kk = 0; kk < 6; ++kk)
        qf[kk] = *(const bf16x8*)(qp + qkb +
            (size_t)(q0 + (w << 4) + li) * 192 + kk * 32 + (g << 3));

    float mst[4], lst[4];
    f32x4 oacc[8];
    #pragma unroll
    for (int r = 0; r < 4; ++r) { mst[r] = NEGINF; lst[r] = 0.f; }
    #pragma unroll
    for (int ct = 0; ct < 8; ++ct) oacc[ct] = (f32x4){0.f, 0.f, 0.f, 0.f};

    for (int t = 0; t <= qt; ++t) {
        const int j0 = t << 6;
        __syncthreads();
        #pragma unroll
        for (int p = 0; p < 6; ++p) {
            int idx2 = tid + p * 256;
            int r = idx2 / 24, c8 = (idx2 - r * 24) << 3;
            *(bf16x8*)&Ks[r][c8] = *(const bf16x8*)(kp + qkb + (size_t)(j0 + r) * 192 + c8);
        }
        #pragma unroll
        for (int p = 0; p < 8; ++p) {
            int idx2 = tid + p * 256;
            int r = idx2 >> 4, c4 = (idx2 & 15) << 2;
            *(ushort4*)&Vs[r][c4] = *(const ushort4*)(vt + vtb + (size_t)r * 2048 + j0 + c4);
        }
        __syncthreads();

        // S = Q K^T
        f32x4 sacc[4];
        #pragma unroll
        for (int c = 0; c < 4; ++c) sacc[c] = (f32x4){0.f, 0.f, 0.f, 0.f};
        #pragma unroll
        for (int c = 0; c < 4; ++c) {
            #pragma unroll
            for (int kk = 0; kk < 6; ++kk) {
                bf16x8 kf = *(const bf16x8*)&Ks[(c << 4) + li][kk * 32 + (g << 3)];
                sacc[c] = __builtin_amdgcn_mfma_f32_16x16x32_bf16(qf[kk], kf, sacc[c], 0, 0, 0);
            }
        }

        // online softmax; mask only on the diagonal tile; per-row defer-max
        const bool diag = (t == qt);
        float corr[4];
        bool needscale = false;
        #pragma unroll
        for (int r = 0; r < 4; ++r) {
            float sv[4];
            float mx = NEGINF;
            #pragma unroll
            for (int c = 0; c < 4; ++c) {
                float s = sacc[c][r] * scl;
                if (diag) {
                    int colk = j0 + (c << 4) + li;
                    int rq = q0 + (w << 4) + (g << 2) + r;
                    s = (colk <= rq) ? s : NEGINF;
                }
                sv[c] = s;
                mx = fmaxf(mx, s);
            }
            float mold = mst[r];
            float mnew, cr;
            if (__all(mx <= mold + 8.f)) {
                mnew = mold; cr = 1.f;              // defer: keep old max
            } else {
                #pragma unroll
                for (int off = 8; off >= 1; off >>= 1) mx = fmaxf(mx, __shfl_xor(mx, off, 64));
                mnew = fmaxf(mold, mx);
                cr = exp2f(mold - mnew);
                needscale = true;
            }
            mst[r] = mnew;
            corr[r] = cr;
            float psum = 0.f;
            #pragma unroll
            for (int c = 0; c < 4; ++c) {
                float p = exp2f(sv[c] - mnew);
                psum += p;
                Ps[w][(g << 2) + r][(c << 4) + li] = f2bf(p);
            }
            #pragma unroll
            for (int off = 8; off >= 1; off >>= 1) psum += __shfl_xor(psum, off, 64);
            lst[r] = lst[r] * cr + psum;
        }

        // O = O*corr + P V (rescale skipped when all rows deferred)
        if (needscale) {
            #pragma unroll
            for (int ct = 0; ct < 8; ++ct)
                #pragma unroll
                for (int r = 0; r < 4; ++r) oacc[ct][r] *= corr[r];
        }

        bf16x8 pf0 = *(const bf16x8*)&Ps[w][li][(g << 3)];
        bf16x8 pf1 = *(const bf16x8*)&Ps[w][li][32 + (g << 3)];
        #pragma unroll
        for (int ct = 0; ct < 8; ++ct) {
            bf16x8 vf0 = *(const bf16x8*)&Vs[(ct << 4) + li][(g << 3)];
            bf16x8 vf1 = *(const bf16x8*)&Vs[(ct << 4) + li][32 + (g << 3)];
            oacc[ct] = __builtin_amdgcn_mfma_f32_16x16x32_bf16(pf0, vf0, oacc[ct], 0, 0, 0);
            oacc[ct] = __builtin_amdgcn_mfma_f32_16x16x32_bf16(pf1, vf1, oacc[ct], 0, 0, 0);
        }
    }

    #pragma unroll
    for (int r = 0; r < 4; ++r) {
        float inv = 1.f / lst[r];
        int rq = q0 + (w << 4) + (g << 2) + r;
        size_t obase = ((size_t)(b * 2048 + rq) * 2048) + h * 128;
        #pragma unroll
        for (int ct = 0; ct < 8; ++ct)
            yf[obase + (ct << 4) + li] = f2bf(oacc[ct][r] * inv);
    }
}

// ---------------------------------------------------------------------------
extern "C" void kernel_launch(void* const* d_in, const int* in_sizes, int n_in,
                              void* d_out, int out_size, void* d_ws, size_t ws_size,
                              hipStream_t stream)
{
    const float* x     = (const float*)d_in[0];
    const float* fcos  = (const float*)d_in[1];
    const float* fsin  = (const float*)d_in[2];
    const float* W_dq  = (const float*)d_in[3];
    const float* b_dq  = (const float*)d_in[4];
    const float* W_uq  = (const float*)d_in[5];
    const float* b_uq  = (const float*)d_in[6];
    const float* W_qr  = (const float*)d_in[7];
    const float* b_qr  = (const float*)d_in[8];
    const float* W_dkv = (const float*)d_in[9];
    const float* b_dkv = (const float*)d_in[10];
    const float* W_uk  = (const float*)d_in[11];
    const float* b_uk  = (const float*)d_in[12];
    const float* W_uv  = (const float*)d_in[13];
    const float* b_uv  = (const float*)d_in[14];
    const float* W_kr  = (const float*)d_in[15];
    const float* b_kr  = (const float*)d_in[16];
    const float* W_out = (const float*)d_in[17];
    const float* b_out = (const float*)d_in[18];

    char* ws = (char*)d_ws;
    // Layout (R9/R11-verified), peak = 109,576,192 bytes. Aliases:
    //   Wcat2/Wcat3 inside xb region (converted AFTER G1 consumes xb; dead
    //     before attn writes yf over the region)
    //   Wcat1 at vt base (conv->G1, dead before G3 writes vt)
    uint16_t* xb     = (uint16_t*)(ws + 0);              // 4096x2048   [end 16,777,216]
    uint16_t* Wcat2  = (uint16_t*)(ws + 0);              // 3072x1536   ALIAS (post-G1)
    uint16_t* Wcat3  = (uint16_t*)(ws + 9437184);        // 4096x512    ALIAS (post-G1)
    uint16_t* yf     = (uint16_t*)(ws + 0);              // 4096x2048   ALIAS (attn)
    uint16_t* Wout_b = (uint16_t*)(ws + 16777216);       // 2048x2048   [end 25,165,824]
    uint16_t* qp     = (uint16_t*)(ws + 25165824);       // (2,16,2048,192) [end 50,331,648]
    uint16_t* kp     = (uint16_t*)(ws + 50331648);       // (2,16,2048,192) [end 75,497,472]
    uint16_t* vt     = (uint16_t*)(ws + 75497472);       // (2,16,128,2048) [end 92,274,688]
    uint16_t* Wcat1  = (uint16_t*)(ws + 75497472);       // 2176x2048   ALIAS (pre-G3)
    uint16_t* c_all  = (uint16_t*)(ws + 92274688);       // 4096x2112   [end 109,576,192]

    dim3 blk(256);
    // Phase 1 conversions (ONE launch, 5 jobs; quad counts, grid exact):
    //   x(2097152), Wdq(786432), Wdkv(262144), Wkr(32768 src/65536 dst), Wout(1048576)
    conv_multi<<<dim3(16640), blk, 0, stream>>>(
        x,     xb,              2097152, 2097152,
        W_dq,  Wcat1,            786432,  786432,
        W_dkv, Wcat1 + 3145728,  262144,  262144,
        W_kr,  Wcat1 + 4194304,   32768,   65536,
        W_out, Wout_b,          1048576, 1048576);

    // G1: c_all = xb @ Wcat1^T  (N=2112, bias regions 1536/2048)
    gemm_fused<0><<<dim3(17, 32), blk, 0, stream>>>(
        xb, Wcat1, b_dq, b_dkv, b_kr, nullptr, nullptr, c_all, nullptr,
        4096, 2112, 2048, /*lda*/2048, 1536, 2048);
    // --- xb dead; Wcat1 dead ---

    // Phase 2 conversions (ONE launch, 4 jobs into xb region):
    //   Wuq(786432), Wqr(393216), Wuk(262144), Wuv(262144)
    conv_multi<<<dim3(6656), blk, 0, stream>>>(
        W_uq, Wcat2,             786432, 786432,
        W_qr, Wcat2 + 3145728,   393216, 393216,
        W_uk, Wcat3,             262144, 262144,
        W_uv, Wcat3 + 1048576,   262144, 262144,
        nullptr, nullptr, 0, 0);

    // G2: qp = [uq-pack | rope(qr)-pack] = c_q @ Wcat2^T  (A = c_all cols 0..1535)
    gemm_fused<4><<<dim3(24, 32), blk, 0, stream>>>(
        c_all, Wcat2, b_uq, b_qr, b_qr, fcos, fsin, qp, nullptr,
        4096, 3072, 1536, /*lda*/2112, 2048, 3072);

    // G3: [kp-pack | vt-pack] = c_kv @ Wcat3^T  (A = c_all cols 1536..2047)
    gemm_fused<5><<<dim3(32, 32), blk, 0, stream>>>(
        c_all + 1536, Wcat3, b_uk, b_uv, b_uv, nullptr, nullptr, kp, vt,
        4096, 4096, 512, /*lda*/2112, 2048, 4096);

    // rope_k: kr columns live at c_all + 2048, row stride 2112
    rope_k_kernel<<<dim3(1024), blk, 0, stream>>>(c_all + 2048, 2112, fcos, fsin, kp);

    // attention: 1024 blocks, heavy-first (writes yf over dead Wcat2/3)
    attn_mfma6<<<dim3(1024), blk, 0, stream>>>(qp, kp, vt, yf);

    // output projection
    gemm_fused<3><<<dim3(16, 32), blk, 0, stream>>>(
        yf, Wout_b, b_out, b_out, b_out, nullptr, nullptr, d_out, nullptr,
        4096, 2048, 2048, /*lda*/2048, 2048, 2048);
}

// Round 13
// 412.657 us; speedup vs baseline: 1.0130x; 1.0130x over previous
//
#include <hip/hip_runtime.h>
#include <hip/hip_bf16.h>
#include <stdint.h>

// MLA forward, B=2 S=2048 DIM=2048 NH=16 HD=128 HDR=64 DCKV=512 DCQ=1536
// Round 13: attn = R11's verified straight-line math (both VALU-cut attempts
// regressed via 2nd-order effects) + T14 register prefetch WITHOUT the R7
// VGPR cap: LDS binds occupancy at 3 blocks/CU (12 waves), which tolerates
// VGPR<=170; R11@112 + 40 prefetch regs ~ 150 < 170 -> occupancy preserved.
// conv_multi + fused GEMMs + rope_k unchanged from R12 (non-attn 216us).
//
// Reference reshape quirk: q = concat([uq(2048), rq(1024)]).reshape(...,16,192)
// -> head h owns FLAT dims [192h,192h+192) of the concat (same for k).

typedef __bf16 bf16x8 __attribute__((ext_vector_type(8)));
typedef float  f32x4  __attribute__((ext_vector_type(4)));

__device__ __forceinline__ uint16_t f2bf(float f) {
    uint32_t u = __builtin_bit_cast(uint32_t, f);
    u = (u + 0x7FFFu + ((u >> 16) & 1u)) >> 16;
    return (uint16_t)u;
}
__device__ __forceinline__ float bf2f(uint16_t h) {
    uint32_t u = ((uint32_t)h) << 16;
    return __builtin_bit_cast(float, u);
}

typedef __attribute__((address_space(3))) uint32_t lds_u32_t;
typedef const __attribute__((address_space(1))) uint32_t glb_u32_t;

__device__ __forceinline__ void gld16(const void* g, const void* l) {
    __builtin_amdgcn_global_load_lds((glb_u32_t*)(uintptr_t)g,
                                     (lds_u32_t*)(uint32_t)(uintptr_t)l, 16, 0, 0);
}

// ---------------------------------------------------------------------------
// Multi-job fp32 -> bf16 conversion (R12-verified). Quad q routes by
// cumulative dst-quad counts; zero-fills beyond src quads (W_kr padding).
// ---------------------------------------------------------------------------
__global__ __launch_bounds__(256)
void conv_multi(const float* __restrict__ s0, uint16_t* __restrict__ d0, int q0s, int q0d,
                const float* __restrict__ s1, uint16_t* __restrict__ d1, int q1s, int q1d,
                const float* __restrict__ s2, uint16_t* __restrict__ d2, int q2s, int q2d,
                const float* __restrict__ s3, uint16_t* __restrict__ d3, int q3s, int q3d,
                const float* __restrict__ s4, uint16_t* __restrict__ d4, int q4s, int q4d)
{
    int q = blockIdx.x * 256 + threadIdx.x;
    const float* s; uint16_t* d; int qs;
    if (q < q0d)                    { s = s0; d = d0; qs = q0s; }
    else if ((q -= q0d) < q1d)      { s = s1; d = d1; qs = q1s; }
    else if ((q -= q1d) < q2d)      { s = s2; d = d2; qs = q2s; }
    else if ((q -= q2d) < q3d)      { s = s3; d = d3; qs = q3s; }
    else if ((q -= q3d) < q4d)      { s = s4; d = d4; qs = q4s; }
    else return;
    int i = q << 2;
    ushort4 o;
    if (q < qs) {
        float4 v = *(const float4*)(s + i);
        o.x = f2bf(v.x); o.y = f2bf(v.y); o.z = f2bf(v.z); o.w = f2bf(v.w);
    } else {
        o.x = 0; o.y = 0; o.z = 0; o.w = 0;
    }
    *(ushort4*)(d + i) = o;
}

// ---------------------------------------------------------------------------
// Fused GEMM (R11/R12-verified, unchanged): C(M,N) = A(M,K;lda) @ W(N,K)^T + bias.
// MODE 0: bf16 row-major  MODE 3: fp32 row-major
// MODE 4: qk-pack | FUSED ROPE-Q   MODE 5: qk-pack | v-transpose-pack
// ---------------------------------------------------------------------------
template<int MODE>
__global__ __launch_bounds__(256, 2)
void gemm_fused(const uint16_t* __restrict__ A, const uint16_t* __restrict__ W,
                const float* __restrict__ b0, const float* __restrict__ b1,
                const float* __restrict__ b2,
                const float* __restrict__ fc, const float* __restrict__ fs,
                void* __restrict__ O0, void* __restrict__ O1,
                int M, int N, int K, int lda, int s1, int s2)
{
    __shared__ __align__(16) uint16_t Alds[128 * 32];
    __shared__ __align__(16) uint16_t Blds[128 * 32];

    const int tid  = threadIdx.x;
    const int lane = tid & 63;
    const int wave = tid >> 6;
    const int wm   = wave >> 1;
    const int wn   = wave & 1;
    const int m0   = blockIdx.y << 7;
    const int n0   = blockIdx.x << 7;

    f32x4 acc[4][4];
    #pragma unroll
    for (int i = 0; i < 4; ++i)
        #pragma unroll
        for (int j = 0; j < 4; ++j)
            acc[i][j] = (f32x4){0.f, 0.f, 0.f, 0.f};

    const int r0 = (wave << 5) + (lane >> 2);
    const int ck = (lane & 3) << 3;
    const uint16_t* gA0 = A + (size_t)(m0 + r0) * lda + ck;
    const uint16_t* gA1 = gA0 + (size_t)16 * lda;
    const uint16_t* gB0 = W + (size_t)(n0 + r0) * K + ck;
    const uint16_t* gB1 = gB0 + (size_t)16 * K;
    const uint16_t* lA0 = Alds + (wave << 10);
    const uint16_t* lA1 = lA0 + 512;
    const uint16_t* lB0 = Blds + (wave << 10);
    const uint16_t* lB1 = lB0 + 512;

    const int rsel = lane & 15;
    const int g8   = (lane >> 4) << 3;

    const int nK = K >> 5;
    for (int kt = 0; kt < nK; ++kt) {
        __syncthreads();
        gld16(gA0, lA0); gld16(gA1, lA1);
        gld16(gB0, lB0); gld16(gB1, lB1);
        gA0 += 32; gA1 += 32; gB0 += 32; gB1 += 32;
        __syncthreads();

        bf16x8 af[4], bfr[4];
        #pragma unroll
        for (int i = 0; i < 4; ++i)
            af[i] = *(const bf16x8*)&Alds[(((wm << 6) + (i << 4) + rsel) << 5) + g8];
        #pragma unroll
        for (int j = 0; j < 4; ++j)
            bfr[j] = *(const bf16x8*)&Blds[(((wn << 6) + (j << 4) + rsel) << 5) + g8];

        #pragma unroll
        for (int i = 0; i < 4; ++i)
            #pragma unroll
            for (int j = 0; j < 4; ++j)
                acc[i][j] = __builtin_amdgcn_mfma_f32_16x16x32_bf16(af[i], bfr[j], acc[i][j], 0, 0, 0);
    }

    // epilogue: D lane map: col = lane&15, row = 4*(lane>>4)+r
    const int col = lane & 15;
    const int rg  = lane >> 4;
    #pragma unroll
    for (int i = 0; i < 4; ++i) {
        #pragma unroll
        for (int j = 0; j < 4; ++j) {
            int n = n0 + (wn << 6) + (j << 4) + col;
            if (n >= N) continue;
            float bv = (n < s1) ? b0[n] : (n < s2) ? b1[n - s1] : b2[n - s2];
            float v[4];
            #pragma unroll
            for (int r = 0; r < 4; ++r) v[r] = acc[i][j][r] + bv;
            int mbase = m0 + (wm << 6) + (i << 4) + (rg << 2);
            if (MODE == 0) {
                uint16_t* o = (uint16_t*)O0 + (size_t)mbase * N + n;
                #pragma unroll
                for (int r = 0; r < 4; ++r) o[(size_t)r * N] = f2bf(v[r]);
            } else if (MODE == 3) {
                float* o = (float*)O0 + (size_t)mbase * N + n;
                #pragma unroll
                for (int r = 0; r < 4; ++r) o[(size_t)r * N] = v[r];
            } else {
                int b = mbase >> 11, s = mbase & 2047;
                if (n < s1) {           // qk-pack (n < 2048, hh = n/192)
                    int hh = n / 192, d = n - hh * 192;
                    uint16_t* o = (uint16_t*)O0 + (((size_t)(b * 16 + hh) * 2048 + s) * 192) + d;
                    #pragma unroll
                    for (int r = 0; r < 4; ++r) o[r * 192] = f2bf(v[r]);
                } else if (MODE == 4) { // FUSED ROPE-Q -> qp
                    int nn = n - s1;
                    int d  = nn & 63;
                    float bp = b1[nn ^ 32];
                    int f = 2048 + nn;
                    int head = f / 192, dq = f - head * 192;
                    uint16_t* o = (uint16_t*)O0 + (((size_t)(b * 16 + head) * 2048 + s) * 192) + dq;
                    #pragma unroll
                    for (int r = 0; r < 4; ++r) {
                        float pv  = acc[i][j ^ 2][r] + bp;
                        float rot = (d < 32) ? -pv : pv;
                        int   sl  = s + r;
                        float out = v[r] * fc[(size_t)sl * 64 + d] + rot * fs[(size_t)sl * 64 + d];
                        o[r * 192] = f2bf(out);
                    }
                } else {                // MODE 5: v-transpose pack
                    int nn = n - s1;
                    int hh = nn >> 7, d = nn & 127;
                    ushort4 o4;
                    o4.x = f2bf(v[0]); o4.y = f2bf(v[1]); o4.z = f2bf(v[2]); o4.w = f2bf(v[3]);
                    *(ushort4*)&((uint16_t*)O1)[(((size_t)(b * 16 + hh) * 128 + d) * 2048) + s] = o4;
                }
            }
        }
    }
}

// ---------------------------------------------------------------------------
// rope_k (R11-verified, unchanged)
// ---------------------------------------------------------------------------
__global__ __launch_bounds__(256)
void rope_k_kernel(const uint16_t* __restrict__ raw, int ldr,
                   const float* __restrict__ fc, const float* __restrict__ fs,
                   uint16_t* __restrict__ kp)
{
    int gid = blockIdx.x * 256 + threadIdx.x;
    int m = gid >> 6, d = gid & 63;
    int b = m >> 11, s = m & 2047;
    float x  = bf2f(raw[(size_t)m * ldr + d]);
    float xo = bf2f(raw[(size_t)m * ldr + ((d < 32) ? d + 32 : d - 32)]);
    float rot = (d < 32) ? -xo : xo;
    uint16_t bv = f2bf(x * fc[s * 64 + d] + rot * fs[s * 64 + d]);
    #pragma unroll
    for (int hh = 0; hh < 16; ++hh) {
        int f = 2048 + hh * 64 + d;
        int head = f / 192, dk = f - head * 192;
        kp[(((size_t)(b * 16 + head) * 2048 + s) * 192) + dk] = bv;
    }
}

// ---------------------------------------------------------------------------
// MFMA flash attention (causal). R11 grid + R11 straight-line softmax math +
// T14 register prefetch (no VGPR cap): K loads issued before QK, V loads
// after QK, LDS writes after the post-PV barrier.
// ---------------------------------------------------------------------------
__global__ __launch_bounds__(256)
void attn_mfma7(const uint16_t* __restrict__ qp, const uint16_t* __restrict__ kp,
                const uint16_t* __restrict__ vt, uint16_t* __restrict__ yf)
{
    __shared__ uint16_t Ks[64][200];
    __shared__ uint16_t Vs[128][72];
    __shared__ uint16_t Ps[4][16][72];

    const int tid  = threadIdx.x;
    const int lane = tid & 63;
    const int w    = tid >> 6;
    const int g    = lane >> 4;
    const int li   = lane & 15;
    const int idx  = blockIdx.x;
    const int qt   = 31 - (idx >> 5);      // heavy tiles dispatch first
    const int bh   = idx & 31;             // idx%8 == bh%8 -> same-head same-XCD
    const int b    = bh >> 4;
    const int h    = bh & 15;
    const int q0   = qt << 6;

    const size_t qkb = (size_t)bh * 2048 * 192;
    const size_t vtb = (size_t)bh * 128 * 2048;
    const float scl = 0.07216878364870323f * 1.4426950408889634f;  // 1/sqrt(192)*log2e

    // Q fragments: wave owns rows q0 + w*16 .. +15
    bf16x8 qf[6];
    #pragma unroll
    for (int kk = 0; kk < 6; ++kk)
        qf[kk] = *(const bf16x8*)(qp + qkb +
            (size_t)(q0 + (w << 4) + li) * 192 + kk * 32 + (g << 3));

    float mst[4], lst[4];
    f32x4 oacc[8];
    #pragma unroll
    for (int r = 0; r < 4; ++r) { mst[r] = -__builtin_inff(); lst[r] = 0.f; }
    #pragma unroll
    for (int ct = 0; ct < 8; ++ct) oacc[ct] = (f32x4){0.f, 0.f, 0.f, 0.f};

    // staging maps
    int krp[6], kcp[6], vrp[8], vcp[8];
    #pragma unroll
    for (int p = 0; p < 6; ++p) {
        int i2 = tid + p * 256;
        krp[p] = i2 / 24; kcp[p] = (i2 - krp[p] * 24) << 3;
    }
    #pragma unroll
    for (int p = 0; p < 8; ++p) {
        int i2 = tid + p * 256;
        vrp[p] = i2 >> 4; vcp[p] = (i2 & 15) << 2;
    }

    bf16x8  kreg[6];
    ushort4 vreg[8];

    // prologue: stage tile 0
    #pragma unroll
    for (int p = 0; p < 6; ++p)
        kreg[p] = *(const bf16x8*)(kp + qkb + (size_t)krp[p] * 192 + kcp[p]);
    #pragma unroll
    for (int p = 0; p < 8; ++p)
        vreg[p] = *(const ushort4*)(vt + vtb + (size_t)vrp[p] * 2048 + vcp[p]);
    #pragma unroll
    for (int p = 0; p < 6; ++p) *(bf16x8*)&Ks[krp[p]][kcp[p]] = kreg[p];
    #pragma unroll
    for (int p = 0; p < 8; ++p) *(ushort4*)&Vs[vrp[p]][vcp[p]] = vreg[p];
    __syncthreads();

    for (int t = 0; t <= qt; ++t) {
        const int j0n = (t + 1) << 6;
        const bool pre = (t < qt);

        // issue next K loads (hidden under QK + softmax + PV)
        if (pre) {
            #pragma unroll
            for (int p = 0; p < 6; ++p)
                kreg[p] = *(const bf16x8*)(kp + qkb + (size_t)(j0n + krp[p]) * 192 + kcp[p]);
        }

        // S = Q K^T
        f32x4 sacc[4];
        #pragma unroll
        for (int c = 0; c < 4; ++c) sacc[c] = (f32x4){0.f, 0.f, 0.f, 0.f};
        #pragma unroll
        for (int c = 0; c < 4; ++c) {
            #pragma unroll
            for (int kk = 0; kk < 6; ++kk) {
                bf16x8 kf = *(const bf16x8*)&Ks[(c << 4) + li][kk * 32 + (g << 3)];
                sacc[c] = __builtin_amdgcn_mfma_f32_16x16x32_bf16(qf[kk], kf, sacc[c], 0, 0, 0);
            }
        }

        // issue next V loads (hidden under softmax + PV)
        if (pre) {
            #pragma unroll
            for (int p = 0; p < 8; ++p)
                vreg[p] = *(const ushort4*)(vt + vtb + (size_t)vrp[p] * 2048 + j0n + vcp[p]);
        }

        // online softmax (R11 straight-line form; rows in 16-lane groups)
        const int j0 = t << 6;
        float corr[4];
        #pragma unroll
        for (int r = 0; r < 4; ++r) {
            const int rq = q0 + (w << 4) + (g << 2) + r;
            float sv[4];
            float mx = -__builtin_inff();
            #pragma unroll
            for (int c = 0; c < 4; ++c) {
                int colk = j0 + (c << 4) + li;
                sv[c] = (colk <= rq) ? sacc[c][r] * scl : -__builtin_inff();
                mx = fmaxf(mx, sv[c]);
            }
            #pragma unroll
            for (int off = 8; off >= 1; off >>= 1) mx = fmaxf(mx, __shfl_xor(mx, off, 64));
            float mnew = fmaxf(mst[r], mx);
            corr[r] = exp2f(mst[r] - mnew);
            mst[r] = mnew;
            float psum = 0.f;
            #pragma unroll
            for (int c = 0; c < 4; ++c) {
                float p = exp2f(sv[c] - mnew);
                psum += p;
                Ps[w][(g << 2) + r][(c << 4) + li] = f2bf(p);
            }
            #pragma unroll
            for (int off = 8; off >= 1; off >>= 1) psum += __shfl_xor(psum, off, 64);
            lst[r] = lst[r] * corr[r] + psum;
        }

        // O = O*corr + P V
        #pragma unroll
        for (int ct = 0; ct < 8; ++ct)
            #pragma unroll
            for (int r = 0; r < 4; ++r) oacc[ct][r] *= corr[r];

        bf16x8 pf0 = *(const bf16x8*)&Ps[w][li][(g << 3)];
        bf16x8 pf1 = *(const bf16x8*)&Ps[w][li][32 + (g << 3)];
        #pragma unroll
        for (int ct = 0; ct < 8; ++ct) {
            bf16x8 vf0 = *(const bf16x8*)&Vs[(ct << 4) + li][(g << 3)];
            bf16x8 vf1 = *(const bf16x8*)&Vs[(ct << 4) + li][32 + (g << 3)];
            oacc[ct] = __builtin_amdgcn_mfma_f32_16x16x32_bf16(pf0, vf0, oacc[ct], 0, 0, 0);
            oacc[ct] = __builtin_amdgcn_mfma_f32_16x16x32_bf16(pf1, vf1, oacc[ct], 0, 0, 0);
        }

        __syncthreads();   // all waves done reading Ks/Vs for tile t
        if (pre) {
            #pragma unroll
            for (int p = 0; p < 6; ++p) *(bf16x8*)&Ks[krp[p]][kcp[p]] = kreg[p];
            #pragma unroll
            for (int p = 0; p < 8; ++p) *(ushort4*)&Vs[vrp[p]][vcp[p]] = vreg[p];
            __syncthreads();
        }
    }

    #pragma unroll
    for (int r = 0; r < 4; ++r) {
        float inv = 1.f / lst[r];
        int rq = q0 + (w << 4) + (g << 2) + r;
        size_t obase = ((size_t)(b * 2048 + rq) * 2048) + h * 128;
        #pragma unroll
        for (int ct = 0; ct < 8; ++ct)
            yf[obase + (ct << 4) + li] = f2bf(oacc[ct][r] * inv);
    }
}

// ---------------------------------------------------------------------------
extern "C" void kernel_launch(void* const* d_in, const int* in_sizes, int n_in,
                              void* d_out, int out_size, void* d_ws, size_t ws_size,
                              hipStream_t stream)
{
    const float* x     = (const float*)d_in[0];
    const float* fcos  = (const float*)d_in[1];
    const float* fsin  = (const float*)d_in[2];
    const float* W_dq  = (const float*)d_in[3];
    const float* b_dq  = (const float*)d_in[4];
    const float* W_uq  = (const float*)d_in[5];
    const float* b_uq  = (const float*)d_in[6];
    const float* W_qr  = (const float*)d_in[7];
    const float* b_qr  = (const float*)d_in[8];
    const float* W_dkv = (const float*)d_in[9];
    const float* b_dkv = (const float*)d_in[10];
    const float* W_uk  = (const float*)d_in[11];
    const float* b_uk  = (const float*)d_in[12];
    const float* W_uv  = (const float*)d_in[13];
    const float* b_uv  = (const float*)d_in[14];
    const float* W_kr  = (const float*)d_in[15];
    const float* b_kr  = (const float*)d_in[16];
    const float* W_out = (const float*)d_in[17];
    const float* b_out = (const float*)d_in[18];

    char* ws = (char*)d_ws;
    // Layout (R9/R11-verified), peak = 109,576,192 bytes. Aliases:
    //   Wcat2/Wcat3 inside xb region (converted AFTER G1 consumes xb; dead
    //     before attn writes yf over the region)
    //   Wcat1 at vt base (conv->G1, dead before G3 writes vt)
    uint16_t* xb     = (uint16_t*)(ws + 0);              // 4096x2048   [end 16,777,216]
    uint16_t* Wcat2  = (uint16_t*)(ws + 0);              // 3072x1536   ALIAS (post-G1)
    uint16_t* Wcat3  = (uint16_t*)(ws + 9437184);        // 4096x512    ALIAS (post-G1)
    uint16_t* yf     = (uint16_t*)(ws + 0);              // 4096x2048   ALIAS (attn)
    uint16_t* Wout_b = (uint16_t*)(ws + 16777216);       // 2048x2048   [end 25,165,824]
    uint16_t* qp     = (uint16_t*)(ws + 25165824);       // (2,16,2048,192) [end 50,331,648]
    uint16_t* kp     = (uint16_t*)(ws + 50331648);       // (2,16,2048,192) [end 75,497,472]
    uint16_t* vt     = (uint16_t*)(ws + 75497472);       // (2,16,128,2048) [end 92,274,688]
    uint16_t* Wcat1  = (uint16_t*)(ws + 75497472);       // 2176x2048   ALIAS (pre-G3)
    uint16_t* c_all  = (uint16_t*)(ws + 92274688);       // 4096x2112   [end 109,576,192]

    dim3 blk(256);
    // Phase 1 conversions (ONE launch, 5 jobs; quad counts, grid exact)
    conv_multi<<<dim3(16640), blk, 0, stream>>>(
        x,     xb,              2097152, 2097152,
        W_dq,  Wcat1,            786432,  786432,
        W_dkv, Wcat1 + 3145728,  262144,  262144,
        W_kr,  Wcat1 + 4194304,   32768,   65536,
        W_out, Wout_b,          1048576, 1048576);

    // G1: c_all = xb @ Wcat1^T  (N=2112, bias regions 1536/2048)
    gemm_fused<0><<<dim3(17, 32), blk, 0, stream>>>(
        xb, Wcat1, b_dq, b_dkv, b_kr, nullptr, nullptr, c_all, nullptr,
        4096, 2112, 2048, /*lda*/2048, 1536, 2048);
    // --- xb dead; Wcat1 dead ---

    // Phase 2 conversions (ONE launch, 4 jobs into xb region)
    conv_multi<<<dim3(6656), blk, 0, stream>>>(
        W_uq, Wcat2,             786432, 786432,
        W_qr, Wcat2 + 3145728,   393216, 393216,
        W_uk, Wcat3,             262144, 262144,
        W_uv, Wcat3 + 1048576,   262144, 262144,
        nullptr, nullptr, 0, 0);

    // G2: qp = [uq-pack | rope(qr)-pack] = c_q @ Wcat2^T  (A = c_all cols 0..1535)
    gemm_fused<4><<<dim3(24, 32), blk, 0, stream>>>(
        c_all, Wcat2, b_uq, b_qr, b_qr, fcos, fsin, qp, nullptr,
        4096, 3072, 1536, /*lda*/2112, 2048, 3072);

    // G3: [kp-pack | vt-pack] = c_kv @ Wcat3^T  (A = c_all cols 1536..2047)
    gemm_fused<5><<<dim3(32, 32), blk, 0, stream>>>(
        c_all + 1536, Wcat3, b_uk, b_uv, b_uv, nullptr, nullptr, kp, vt,
        4096, 4096, 512, /*lda*/2112, 2048, 4096);

    // rope_k: kr columns live at c_all + 2048, row stride 2112
    rope_k_kernel<<<dim3(1024), blk, 0, stream>>>(c_all + 2048, 2112, fcos, fsin, kp);

    // attention: 1024 blocks, heavy-first, T14 prefetch (writes yf over dead Wcat2/3)
    attn_mfma7<<<dim3(1024), blk, 0, stream>>>(qp, kp, vt, yf);

    // output projection
    gemm_fused<3><<<dim3(16, 32), blk, 0, stream>>>(
        yf, Wout_b, b_out, b_out, b_out, nullptr, nullptr, d_out, nullptr,
        4096, 2048, 2048, /*lda*/2048, 2048, 2048);
}

// Round 14
// 332.916 us; speedup vs baseline: 1.2556x; 1.2395x over previous
//
#include <hip/hip_runtime.h>
#include <hip/hip_bf16.h>
#include <stdint.h>

// MLA forward, B=2 S=2048 DIM=2048 NH=16 HD=128 HDR=64 DCKV=512 DCQ=1536
// Round 14: best-known combine + one cheap experiment.
//  - attn: R11's attn_mfma5 BYTE-IDENTICAL (138us; R10/R12/R13 all regressed
//    via VGPR-cliff@128 / branch-ILP / VGPR-cliff@128 respectively).
//  - conv_multi (R12, verified small win).
//  - NEW: chunked XCD swizzle on all GEMM grids (bijective, nwg%8==0):
//    each XCD gets a contiguous block-id chunk -> A-panels fetched 1x not 8x.
//
// Reference reshape quirk: q = concat([uq(2048), rq(1024)]).reshape(...,16,192)
// -> head h owns FLAT dims [192h,192h+192) of the concat (same for k).

typedef __bf16 bf16x8 __attribute__((ext_vector_type(8)));
typedef float  f32x4  __attribute__((ext_vector_type(4)));

__device__ __forceinline__ uint16_t f2bf(float f) {
    uint32_t u = __builtin_bit_cast(uint32_t, f);
    u = (u + 0x7FFFu + ((u >> 16) & 1u)) >> 16;
    return (uint16_t)u;
}
__device__ __forceinline__ float bf2f(uint16_t h) {
    uint32_t u = ((uint32_t)h) << 16;
    return __builtin_bit_cast(float, u);
}

typedef __attribute__((address_space(3))) uint32_t lds_u32_t;
typedef const __attribute__((address_space(1))) uint32_t glb_u32_t;

__device__ __forceinline__ void gld16(const void* g, const void* l) {
    __builtin_amdgcn_global_load_lds((glb_u32_t*)(uintptr_t)g,
                                     (lds_u32_t*)(uint32_t)(uintptr_t)l, 16, 0, 0);
}

// ---------------------------------------------------------------------------
// Multi-job fp32 -> bf16 conversion (R12-verified).
// ---------------------------------------------------------------------------
__global__ __launch_bounds__(256)
void conv_multi(const float* __restrict__ s0, uint16_t* __restrict__ d0, int q0s, int q0d,
                const float* __restrict__ s1, uint16_t* __restrict__ d1, int q1s, int q1d,
                const float* __restrict__ s2, uint16_t* __restrict__ d2, int q2s, int q2d,
                const float* __restrict__ s3, uint16_t* __restrict__ d3, int q3s, int q3d,
                const float* __restrict__ s4, uint16_t* __restrict__ d4, int q4s, int q4d)
{
    int q = blockIdx.x * 256 + threadIdx.x;
    const float* s; uint16_t* d; int qs;
    if (q < q0d)                    { s = s0; d = d0; qs = q0s; }
    else if ((q -= q0d) < q1d)      { s = s1; d = d1; qs = q1s; }
    else if ((q -= q1d) < q2d)      { s = s2; d = d2; qs = q2s; }
    else if ((q -= q2d) < q3d)      { s = s3; d = d3; qs = q3s; }
    else if ((q -= q3d) < q4d)      { s = s4; d = d4; qs = q4s; }
    else return;
    int i = q << 2;
    ushort4 o;
    if (q < qs) {
        float4 v = *(const float4*)(s + i);
        o.x = f2bf(v.x); o.y = f2bf(v.y); o.z = f2bf(v.z); o.w = f2bf(v.w);
    } else {
        o.x = 0; o.y = 0; o.z = 0; o.w = 0;
    }
    *(ushort4*)(d + i) = o;
}

// ---------------------------------------------------------------------------
// Fused GEMM: C(M,N) = A(M,K;lda) @ W(N,K)^T + bias. A,W bf16; bias fp32.
// m97 structure + chunked XCD swizzle (grid.x*grid.y must be % 8 == 0).
// MODE 0: bf16 row-major  MODE 3: fp32 row-major
// MODE 4: qk-pack | FUSED ROPE-Q   MODE 5: qk-pack | v-transpose-pack
// ---------------------------------------------------------------------------
template<int MODE>
__global__ __launch_bounds__(256, 2)
void gemm_fused(const uint16_t* __restrict__ A, const uint16_t* __restrict__ W,
                const float* __restrict__ b0, const float* __restrict__ b1,
                const float* __restrict__ b2,
                const float* __restrict__ fc, const float* __restrict__ fs,
                void* __restrict__ O0, void* __restrict__ O1,
                int M, int N, int K, int lda, int s1, int s2)
{
    __shared__ __align__(16) uint16_t Alds[128 * 32];
    __shared__ __align__(16) uint16_t Blds[128 * 32];

    const int tid  = threadIdx.x;
    const int lane = tid & 63;
    const int wave = tid >> 6;
    const int wm   = wave >> 1;
    const int wn   = wave & 1;

    // chunked XCD swizzle: consecutive-id round-robin -> per-XCD contiguous
    // chunk (same A-panels stay on one XCD's L2). nwg % 8 == 0 for all grids.
    const int id  = blockIdx.x + gridDim.x * blockIdx.y;
    const int cpx = (gridDim.x * gridDim.y) >> 3;
    const int nid = (id & 7) * cpx + (id >> 3);
    const int m0  = (nid / gridDim.x) << 7;
    const int n0  = (nid % gridDim.x) << 7;

    f32x4 acc[4][4];
    #pragma unroll
    for (int i = 0; i < 4; ++i)
        #pragma unroll
        for (int j = 0; j < 4; ++j)
            acc[i][j] = (f32x4){0.f, 0.f, 0.f, 0.f};

    const int r0 = (wave << 5) + (lane >> 2);
    const int ck = (lane & 3) << 3;
    const uint16_t* gA0 = A + (size_t)(m0 + r0) * lda + ck;
    const uint16_t* gA1 = gA0 + (size_t)16 * lda;
    const uint16_t* gB0 = W + (size_t)(n0 + r0) * K + ck;
    const uint16_t* gB1 = gB0 + (size_t)16 * K;
    const uint16_t* lA0 = Alds + (wave << 10);
    const uint16_t* lA1 = lA0 + 512;
    const uint16_t* lB0 = Blds + (wave << 10);
    const uint16_t* lB1 = lB0 + 512;

    const int rsel = lane & 15;
    const int g8   = (lane >> 4) << 3;

    const int nK = K >> 5;
    for (int kt = 0; kt < nK; ++kt) {
        __syncthreads();
        gld16(gA0, lA0); gld16(gA1, lA1);
        gld16(gB0, lB0); gld16(gB1, lB1);
        gA0 += 32; gA1 += 32; gB0 += 32; gB1 += 32;
        __syncthreads();

        bf16x8 af[4], bfr[4];
        #pragma unroll
        for (int i = 0; i < 4; ++i)
            af[i] = *(const bf16x8*)&Alds[(((wm << 6) + (i << 4) + rsel) << 5) + g8];
        #pragma unroll
        for (int j = 0; j < 4; ++j)
            bfr[j] = *(const bf16x8*)&Blds[(((wn << 6) + (j << 4) + rsel) << 5) + g8];

        #pragma unroll
        for (int i = 0; i < 4; ++i)
            #pragma unroll
            for (int j = 0; j < 4; ++j)
                acc[i][j] = __builtin_amdgcn_mfma_f32_16x16x32_bf16(af[i], bfr[j], acc[i][j], 0, 0, 0);
    }

    // epilogue: D lane map: col = lane&15, row = 4*(lane>>4)+r
    const int col = lane & 15;
    const int rg  = lane >> 4;
    #pragma unroll
    for (int i = 0; i < 4; ++i) {
        #pragma unroll
        for (int j = 0; j < 4; ++j) {
            int n = n0 + (wn << 6) + (j << 4) + col;
            if (n >= N) continue;
            float bv = (n < s1) ? b0[n] : (n < s2) ? b1[n - s1] : b2[n - s2];
            float v[4];
            #pragma unroll
            for (int r = 0; r < 4; ++r) v[r] = acc[i][j][r] + bv;
            int mbase = m0 + (wm << 6) + (i << 4) + (rg << 2);
            if (MODE == 0) {
                uint16_t* o = (uint16_t*)O0 + (size_t)mbase * N + n;
                #pragma unroll
                for (int r = 0; r < 4; ++r) o[(size_t)r * N] = f2bf(v[r]);
            } else if (MODE == 3) {
                float* o = (float*)O0 + (size_t)mbase * N + n;
                #pragma unroll
                for (int r = 0; r < 4; ++r) o[(size_t)r * N] = v[r];
            } else {
                int b = mbase >> 11, s = mbase & 2047;
                if (n < s1) {           // qk-pack (n < 2048, hh = n/192)
                    int hh = n / 192, d = n - hh * 192;
                    uint16_t* o = (uint16_t*)O0 + (((size_t)(b * 16 + hh) * 2048 + s) * 192) + d;
                    #pragma unroll
                    for (int r = 0; r < 4; ++r) o[r * 192] = f2bf(v[r]);
                } else if (MODE == 4) { // FUSED ROPE-Q -> qp
                    int nn = n - s1;
                    int d  = nn & 63;
                    float bp = b1[nn ^ 32];
                    int f = 2048 + nn;
                    int head = f / 192, dq = f - head * 192;
                    uint16_t* o = (uint16_t*)O0 + (((size_t)(b * 16 + head) * 2048 + s) * 192) + dq;
                    #pragma unroll
                    for (int r = 0; r < 4; ++r) {
                        float pv  = acc[i][j ^ 2][r] + bp;
                        float rot = (d < 32) ? -pv : pv;
                        int   sl  = s + r;
                        float out = v[r] * fc[(size_t)sl * 64 + d] + rot * fs[(size_t)sl * 64 + d];
                        o[r * 192] = f2bf(out);
                    }
                } else {                // MODE 5: v-transpose pack
                    int nn = n - s1;
                    int hh = nn >> 7, d = nn & 127;
                    ushort4 o4;
                    o4.x = f2bf(v[0]); o4.y = f2bf(v[1]); o4.z = f2bf(v[2]); o4.w = f2bf(v[3]);
                    *(ushort4*)&((uint16_t*)O1)[(((size_t)(b * 16 + hh) * 128 + d) * 2048) + s] = o4;
                }
            }
        }
    }
}

// ---------------------------------------------------------------------------
// rope_k (R11-verified, unchanged)
// ---------------------------------------------------------------------------
__global__ __launch_bounds__(256)
void rope_k_kernel(const uint16_t* __restrict__ raw, int ldr,
                   const float* __restrict__ fc, const float* __restrict__ fs,
                   uint16_t* __restrict__ kp)
{
    int gid = blockIdx.x * 256 + threadIdx.x;
    int m = gid >> 6, d = gid & 63;
    int b = m >> 11, s = m & 2047;
    float x  = bf2f(raw[(size_t)m * ldr + d]);
    float xo = bf2f(raw[(size_t)m * ldr + ((d < 32) ? d + 32 : d - 32)]);
    float rot = (d < 32) ? -xo : xo;
    uint16_t bv = f2bf(x * fc[s * 64 + d] + rot * fs[s * 64 + d]);
    #pragma unroll
    for (int hh = 0; hh < 16; ++hh) {
        int f = 2048 + hh * 64 + d;
        int head = f / 192, dk = f - head * 192;
        kp[(((size_t)(b * 16 + head) * 2048 + s) * 192) + dk] = bv;
    }
}

// ---------------------------------------------------------------------------
// MFMA flash attention (causal). BYTE-IDENTICAL to R11's attn_mfma5 (138us,
// VGPR 112, verified): 1024 blocks, heavy-first, bh=idx&31 XCD-local K/V.
// ---------------------------------------------------------------------------
__global__ __launch_bounds__(256)
void attn_mfma5(const uint16_t* __restrict__ qp, const uint16_t* __restrict__ kp,
                const uint16_t* __restrict__ vt, uint16_t* __restrict__ yf)
{
    __shared__ uint16_t Ks[64][200];
    __shared__ uint16_t Vs[128][72];
    __shared__ uint16_t Ps[4][16][72];

    const int tid  = threadIdx.x;
    const int lane = tid & 63;
    const int w    = tid >> 6;
    const int g    = lane >> 4;
    const int li   = lane & 15;
    const int idx  = blockIdx.x;
    const int qt   = 31 - (idx >> 5);      // heavy tiles dispatch first
    const int bh   = idx & 31;             // idx%8 == bh%8 -> same-head same-XCD
    const int b    = bh >> 4;
    const int h    = bh & 15;
    const int q0   = qt << 6;

    const size_t qkb = (size_t)bh * 2048 * 192;
    const size_t vtb = (size_t)bh * 128 * 2048;
    const float scl = 0.07216878364870323f * 1.4426950408889634f;  // 1/sqrt(192)*log2e

    // Q fragments: wave owns rows q0 + w*16 .. +15
    bf16x8 qf[6];
    #pragma unroll
    for (int kk = 0; kk < 6; ++kk)
        qf[kk] = *(const bf16x8*)(qp + qkb +
            (size_t)(q0 + (w << 4) + li) * 192 + kk * 32 + (g << 3));

    float mst[4], lst[4];
    f32x4 oacc[8];
    #pragma unroll
    for (int r = 0; r < 4; ++r) { mst[r] = -__builtin_inff(); lst[r] = 0.f; }
    #pragma unroll
    for (int ct = 0; ct < 8; ++ct) oacc[ct] = (f32x4){0.f, 0.f, 0.f, 0.f};

    for (int t = 0; t <= qt; ++t) {
        const int j0 = t << 6;
        __syncthreads();
        #pragma unroll
        for (int p = 0; p < 6; ++p) {
            int idx2 = tid + p * 256;
            int r = idx2 / 24, c8 = (idx2 - r * 24) << 3;
            *(bf16x8*)&Ks[r][c8] = *(const bf16x8*)(kp + qkb + (size_t)(j0 + r) * 192 + c8);
        }
        #pragma unroll
        for (int p = 0; p < 8; ++p) {
            int idx2 = tid + p * 256;
            int r = idx2 >> 4, c4 = (idx2 & 15) << 2;
            *(ushort4*)&Vs[r][c4] = *(const ushort4*)(vt + vtb + (size_t)r * 2048 + j0 + c4);
        }
        __syncthreads();

        // S = Q K^T
        f32x4 sacc[4];
        #pragma unroll
        for (int c = 0; c < 4; ++c) sacc[c] = (f32x4){0.f, 0.f, 0.f, 0.f};
        #pragma unroll
        for (int c = 0; c < 4; ++c) {
            #pragma unroll
            for (int kk = 0; kk < 6; ++kk) {
                bf16x8 kf = *(const bf16x8*)&Ks[(c << 4) + li][kk * 32 + (g << 3)];
                sacc[c] = __builtin_amdgcn_mfma_f32_16x16x32_bf16(qf[kk], kf, sacc[c], 0, 0, 0);
            }
        }

        // online softmax; rows live in 16-lane groups (all 64 lanes active)
        float corr[4];
        #pragma unroll
        for (int r = 0; r < 4; ++r) {
            const int rq = q0 + (w << 4) + (g << 2) + r;
            float sv[4];
            float mx = -__builtin_inff();
            #pragma unroll
            for (int c = 0; c < 4; ++c) {
                int colk = j0 + (c << 4) + li;
                sv[c] = (colk <= rq) ? sacc[c][r] * scl : -__builtin_inff();
                mx = fmaxf(mx, sv[c]);
            }
            #pragma unroll
            for (int off = 8; off >= 1; off >>= 1) mx = fmaxf(mx, __shfl_xor(mx, off, 64));
            float mnew = fmaxf(mst[r], mx);
            corr[r] = exp2f(mst[r] - mnew);
            mst[r] = mnew;
            float psum = 0.f;
            #pragma unroll
            for (int c = 0; c < 4; ++c) {
                float p = exp2f(sv[c] - mnew);
                psum += p;
                Ps[w][(g << 2) + r][(c << 4) + li] = f2bf(p);
            }
            #pragma unroll
            for (int off = 8; off >= 1; off >>= 1) psum += __shfl_xor(psum, off, 64);
            lst[r] = lst[r] * corr[r] + psum;
        }

        // O = O*corr + P V
        #pragma unroll
        for (int ct = 0; ct < 8; ++ct)
            #pragma unroll
            for (int r = 0; r < 4; ++r) oacc[ct][r] *= corr[r];

        bf16x8 pf0 = *(const bf16x8*)&Ps[w][li][(g << 3)];
        bf16x8 pf1 = *(const bf16x8*)&Ps[w][li][32 + (g << 3)];
        #pragma unroll
        for (int ct = 0; ct < 8; ++ct) {
            bf16x8 vf0 = *(const bf16x8*)&Vs[(ct << 4) + li][(g << 3)];
            bf16x8 vf1 = *(const bf16x8*)&Vs[(ct << 4) + li][32 + (g << 3)];
            oacc[ct] = __builtin_amdgcn_mfma_f32_16x16x32_bf16(pf0, vf0, oacc[ct], 0, 0, 0);
            oacc[ct] = __builtin_amdgcn_mfma_f32_16x16x32_bf16(pf1, vf1, oacc[ct], 0, 0, 0);
        }
    }

    #pragma unroll
    for (int r = 0; r < 4; ++r) {
        float inv = 1.f / lst[r];
        int rq = q0 + (w << 4) + (g << 2) + r;
        size_t obase = ((size_t)(b * 2048 + rq) * 2048) + h * 128;
        #pragma unroll
        for (int ct = 0; ct < 8; ++ct)
            yf[obase + (ct << 4) + li] = f2bf(oacc[ct][r] * inv);
    }
}

// ---------------------------------------------------------------------------
extern "C" void kernel_launch(void* const* d_in, const int* in_sizes, int n_in,
                              void* d_out, int out_size, void* d_ws, size_t ws_size,
                              hipStream_t stream)
{
    const float* x     = (const float*)d_in[0];
    const float* fcos  = (const float*)d_in[1];
    const float* fsin  = (const float*)d_in[2];
    const float* W_dq  = (const float*)d_in[3];
    const float* b_dq  = (const float*)d_in[4];
    const float* W_uq  = (const float*)d_in[5];
    const float* b_uq  = (const float*)d_in[6];
    const float* W_qr  = (const float*)d_in[7];
    const float* b_qr  = (const float*)d_in[8];
    const float* W_dkv = (const float*)d_in[9];
    const float* b_dkv = (const float*)d_in[10];
    const float* W_uk  = (const float*)d_in[11];
    const float* b_uk  = (const float*)d_in[12];
    const float* W_uv  = (const float*)d_in[13];
    const float* b_uv  = (const float*)d_in[14];
    const float* W_kr  = (const float*)d_in[15];
    const float* b_kr  = (const float*)d_in[16];
    const float* W_out = (const float*)d_in[17];
    const float* b_out = (const float*)d_in[18];

    char* ws = (char*)d_ws;
    // Layout (R9/R11-verified), peak = 109,576,192 bytes. Aliases:
    //   Wcat2/Wcat3 inside xb region (converted AFTER G1 consumes xb; dead
    //     before attn writes yf over the region)
    //   Wcat1 at vt base (conv->G1, dead before G3 writes vt)
    uint16_t* xb     = (uint16_t*)(ws + 0);              // 4096x2048   [end 16,777,216]
    uint16_t* Wcat2  = (uint16_t*)(ws + 0);              // 3072x1536   ALIAS (post-G1)
    uint16_t* Wcat3  = (uint16_t*)(ws + 9437184);        // 4096x512    ALIAS (post-G1)
    uint16_t* yf     = (uint16_t*)(ws + 0);              // 4096x2048   ALIAS (attn)
    uint16_t* Wout_b = (uint16_t*)(ws + 16777216);       // 2048x2048   [end 25,165,824]
    uint16_t* qp     = (uint16_t*)(ws + 25165824);       // (2,16,2048,192) [end 50,331,648]
    uint16_t* kp     = (uint16_t*)(ws + 50331648);       // (2,16,2048,192) [end 75,497,472]
    uint16_t* vt     = (uint16_t*)(ws + 75497472);       // (2,16,128,2048) [end 92,274,688]
    uint16_t* Wcat1  = (uint16_t*)(ws + 75497472);       // 2176x2048   ALIAS (pre-G3)
    uint16_t* c_all  = (uint16_t*)(ws + 92274688);       // 4096x2112   [end 109,576,192]

    dim3 blk(256);
    // Phase 1 conversions (ONE launch, 5 jobs)
    conv_multi<<<dim3(16640), blk, 0, stream>>>(
        x,     xb,              2097152, 2097152,
        W_dq,  Wcat1,            786432,  786432,
        W_dkv, Wcat1 + 3145728,  262144,  262144,
        W_kr,  Wcat1 + 4194304,   32768,   65536,
        W_out, Wout_b,          1048576, 1048576);

    // G1: c_all = xb @ Wcat1^T  (N=2112, bias regions 1536/2048; 544 blocks % 8 == 0)
    gemm_fused<0><<<dim3(17, 32), blk, 0, stream>>>(
        xb, Wcat1, b_dq, b_dkv, b_kr, nullptr, nullptr, c_all, nullptr,
        4096, 2112, 2048, /*lda*/2048, 1536, 2048);
    // --- xb dead; Wcat1 dead ---

    // Phase 2 conversions (ONE launch, 4 jobs into xb region)
    conv_multi<<<dim3(6656), blk, 0, stream>>>(
        W_uq, Wcat2,             786432, 786432,
        W_qr, Wcat2 + 3145728,   393216, 393216,
        W_uk, Wcat3,             262144, 262144,
        W_uv, Wcat3 + 1048576,   262144, 262144,
        nullptr, nullptr, 0, 0);

    // G2: qp = [uq-pack | rope(qr)-pack] = c_q @ Wcat2^T  (768 blocks)
    gemm_fused<4><<<dim3(24, 32), blk, 0, stream>>>(
        c_all, Wcat2, b_uq, b_qr, b_qr, fcos, fsin, qp, nullptr,
        4096, 3072, 1536, /*lda*/2112, 2048, 3072);

    // G3: [kp-pack | vt-pack] = c_kv @ Wcat3^T  (1024 blocks)
    gemm_fused<5><<<dim3(32, 32), blk, 0, stream>>>(
        c_all + 1536, Wcat3, b_uk, b_uv, b_uv, nullptr, nullptr, kp, vt,
        4096, 4096, 512, /*lda*/2112, 2048, 4096);

    // rope_k: kr columns live at c_all + 2048, row stride 2112
    rope_k_kernel<<<dim3(1024), blk, 0, stream>>>(c_all + 2048, 2112, fcos, fsin, kp);

    // attention: 1024 blocks, heavy-first (writes yf over dead Wcat2/3)
    attn_mfma5<<<dim3(1024), blk, 0, stream>>>(qp, kp, vt, yf);

    // output projection (512 blocks)
    gemm_fused<3><<<dim3(16, 32), blk, 0, stream>>>(
        yf, Wout_b, b_out, b_out, b_out, nullptr, nullptr, d_out, nullptr,
        4096, 2048, 2048, /*lda*/2048, 2048, 2048);
}